// Round 1
// baseline (27.663 us; speedup 1.0000x reference)
//
#include <hip/hip_runtime.h>

// out[b,s,e] = cos(x[b,s,1]) * W_dec[e] + b_dec[e]
// x: (8, 4096, 1024) f32; W_dec: (1024,1) f32; b_dec: (1024,) f32
// out: (8, 4096, 1024) f32. Write-BW bound: 134 MB of stores.

#define EMBED 1024
#define ROWS_PER_BLOCK 16

__global__ __launch_bounds__(256) void vql_kernel(const float* __restrict__ x,
                                                  const float* __restrict__ W,
                                                  const float* __restrict__ b,
                                                  float* __restrict__ out,
                                                  int nrows) {
    const int tid = threadIdx.x;  // 256 threads * float4 = 1024 = one row
    // W/b held in registers for all rows this block touches (8 KB total, L1-hot anyway)
    const float4 w4 = reinterpret_cast<const float4*>(W)[tid];
    const float4 b4 = reinterpret_cast<const float4*>(b)[tid];

    const int row0 = blockIdx.x * ROWS_PER_BLOCK;
#pragma unroll
    for (int r = 0; r < ROWS_PER_BLOCK; ++r) {
        const int row = row0 + r;
        if (row >= nrows) return;
        // uniform-address scalar read; L1/L2 broadcast
        const float c = cosf(x[(size_t)row * EMBED + 1]);
        float4 o;
        o.x = fmaf(c, w4.x, b4.x);
        o.y = fmaf(c, w4.y, b4.y);
        o.z = fmaf(c, w4.z, b4.z);
        o.w = fmaf(c, w4.w, b4.w);
        reinterpret_cast<float4*>(out + (size_t)row * EMBED)[tid] = o;
    }
}

extern "C" void kernel_launch(void* const* d_in, const int* in_sizes, int n_in,
                              void* d_out, int out_size, void* d_ws, size_t ws_size,
                              hipStream_t stream) {
    const float* x = (const float*)d_in[0];
    const float* W = (const float*)d_in[1];
    const float* b = (const float*)d_in[2];
    float* out = (float*)d_out;

    const int nrows = in_sizes[0] / EMBED;  // 8*4096 = 32768
    const int blocks = (nrows + ROWS_PER_BLOCK - 1) / ROWS_PER_BLOCK;  // 2048
    vql_kernel<<<blocks, 256, 0, stream>>>(x, W, b, out, nrows);
}